// Round 4
// baseline (418.533 us; speedup 1.0000x reference)
//
#include <hip/hip_runtime.h>

typedef __bf16 bf16x8 __attribute__((ext_vector_type(8)));
typedef __bf16 bf16x4 __attribute__((ext_vector_type(4)));
typedef float  f32x4  __attribute__((ext_vector_type(4)));

constexpr int kHW = 2304;   // 48*48
constexpr int kC  = 512;

#if __has_builtin(__builtin_amdgcn_exp2f)
#define EXP2(x) __builtin_amdgcn_exp2f(x)
#else
#define EXP2(x) exp2f(x)
#endif

// async global->LDS, 16B per lane. gptr per-lane (base + lane*16B), lptr wave-uniform chunk base.
__device__ __forceinline__ void dma16(const __bf16* g, __bf16* l) {
    __builtin_amdgcn_global_load_lds(
        (const volatile __attribute__((address_space(1))) void*)g,
        (volatile __attribute__((address_space(3))) void*)l, 16, 0, 0);
}

// ---------------------------------------------------------------------------
// K0: weights -> bf16, padded tile-major layouts.
// Wqk2 [kblk=8][128 o][72], Wvb2 [kblk=8][512 c][72]  (cols 64..71 = unused pad)
__global__ void pack_weights(const float* __restrict__ Wq, const float* __restrict__ Wk,
                             const float* __restrict__ Wv, __bf16* __restrict__ Wqk2,
                             __bf16* __restrict__ Wvb2) {
    int idx = blockIdx.x * 256 + threadIdx.x;    // grid 1024 -> 262144
    int o = idx >> 9, k = idx & 511, kb = k >> 6, kr = k & 63;
    if (idx < 64 * 512) {
        Wqk2[((size_t)kb * 128 + o) * 72 + kr]      = (__bf16)Wq[idx];
        Wqk2[((size_t)kb * 128 + 64 + o) * 72 + kr] = (__bf16)Wk[idx];
    }
    if (idx < 512 * 512)
        Wvb2[((size_t)kb * 512 + o) * 72 + kr] = (__bf16)Wv[idx];
}

// ---------------------------------------------------------------------------
// K1: x [B][C][HW] fp32 -> XT2 [b][kblk=8][2304 n][72] bf16 (c-inner, padded rows)
__global__ void pack_x(const float* __restrict__ x, __bf16* __restrict__ XT2) {
    __shared__ __bf16 tile[64][65];              // [c][n]
    int n0 = blockIdx.x * 64, kblk = blockIdx.y, b = blockIdx.z;
    int c0 = kblk * 64;
    int t = threadIdx.x;
    const float* xb = x + (size_t)b * kC * kHW;
#pragma unroll
    for (int rep = 0; rep < 16; ++rep) {
        int c_loc = rep * 4 + (t >> 6);
        int n_loc = t & 63;
        tile[c_loc][n_loc] = (__bf16)xb[(size_t)(c0 + c_loc) * kHW + n0 + n_loc];
    }
    __syncthreads();
    __bf16* dst = XT2 + ((size_t)b * 8 + kblk) * kHW * 72;
#pragma unroll
    for (int rep = 0; rep < 2; ++rep) {
        int item = rep * 256 + t;                // 512 items = 64 n x 8 chunks
        int n_loc = item >> 3, chunk = item & 7;
        bf16x8 v;
#pragma unroll
        for (int j = 0; j < 8; ++j) v[j] = tile[chunk * 8 + j][n_loc];
        *(bf16x8*)(dst + (size_t)(n0 + n_loc) * 72 + chunk * 8) = v;
    }
}

// ---------------------------------------------------------------------------
// K2: QKV projections, m97-style: DMA-staged LDS tiles, BK=64, 2 barriers/iter.
//  type 0:  rows n (A=XT2), cols o (B=Wqk2) -> qbuf [b][n][64] / kbuf (32-row tiles, XOR-swz)
//  type>=1: rows c (A=Wvb2), cols m (B=XT2) -> vbuf2 [b][mblk=72][512 c][40]
// NOTE: Q outputs are pre-scaled by log2(e) so attn can use raw exp2.
// kbuf tile layout: [b][mblk=72][32 m][64 d] with d-slot XOR: elem (m,d) at
//   m*64 + ((d>>3 ^ (m&7))<<3) + (d&7)   -- inverse-swizzled source so the
//   linear global_load_lds DMA lands a bank-conflict-free pattern in LDS.
__global__ __launch_bounds__(256) void qkv_gemm(const __bf16* __restrict__ XT2,
                                                const __bf16* __restrict__ Wqk2,
                                                const __bf16* __restrict__ Wvb2,
                                                const float* __restrict__ bq,
                                                const float* __restrict__ bk,
                                                const float* __restrict__ bv,
                                                __bf16* __restrict__ qbuf,
                                                __bf16* __restrict__ kbuf,
                                                __bf16* __restrict__ vbuf2) {
    __shared__ __align__(16) __bf16 A_lds[128 * 72];
    __shared__ __align__(16) __bf16 B_lds[128 * 72];
    int r0 = blockIdx.x * 128, type = blockIdx.y, b = blockIdx.z;
    int t = threadIdx.x, wave = t >> 6, lane = t & 63, quad = lane >> 4, l16 = lane & 15;

    f32x4 acc[8][2];
#pragma unroll
    for (int i = 0; i < 8; ++i)
#pragma unroll
        for (int j = 0; j < 2; ++j) acc[i][j] = (f32x4){0.f, 0.f, 0.f, 0.f};

    for (int kb = 0; kb < 8; ++kb) {
        const __bf16* Asrc;
        const __bf16* Bsrc;
        if (type == 0) {
            Asrc = XT2 + (((size_t)b * 8 + kb) * kHW + r0) * 72;
            Bsrc = Wqk2 + (size_t)kb * 128 * 72;
        } else {
            Asrc = Wvb2 + ((size_t)kb * 512 + (type - 1) * 128) * 72;
            Bsrc = XT2 + (((size_t)b * 8 + kb) * kHW + r0) * 72;
        }
        __syncthreads();                          // previous iter's LDS reads done
        for (int ch = wave; ch < 18; ch += 4) {   // 18 KB per matrix, 1KB/call
            dma16(Asrc + ch * 512 + lane * 8, &A_lds[ch * 512]);
            dma16(Bsrc + ch * 512 + lane * 8, &B_lds[ch * 512]);
        }
        __syncthreads();                          // DMA complete
#pragma unroll
        for (int dk = 0; dk < 2; ++dk) {
            bf16x8 bfr[2];
#pragma unroll
            for (int ct = 0; ct < 2; ++ct)
                bfr[ct] = *(const bf16x8*)(&B_lds[(wave * 32 + ct * 16 + l16) * 72 + dk * 32 + quad * 8]);
#pragma unroll
            for (int rt = 0; rt < 8; ++rt) {
                bf16x8 a = *(const bf16x8*)(&A_lds[(rt * 16 + l16) * 72 + dk * 32 + quad * 8]);
#pragma unroll
                for (int ct = 0; ct < 2; ++ct)
                    acc[rt][ct] = __builtin_amdgcn_mfma_f32_16x16x32_bf16(a, bfr[ct], acc[rt][ct], 0, 0, 0);
            }
        }
    }

    if (type == 0) {
        constexpr float kLog2e = 1.4426950408889634f;
#pragma unroll
        for (int ct = 0; ct < 2; ++ct) {
            int o = wave * 32 + ct * 16 + l16;
            float bias = (o < 64) ? bq[o] : bk[o - 64];
            float scale = (o < 64) ? kLog2e : 1.0f;   // fold ln2 into Q
#pragma unroll
            for (int rt = 0; rt < 8; ++rt)
#pragma unroll
                for (int r = 0; r < 4; ++r) {
                    int n = r0 + rt * 16 + quad * 4 + r;
                    __bf16 val = (__bf16)((acc[rt][ct][r] + bias) * scale);
                    if (o < 64) {
                        qbuf[((size_t)b * kHW + n) * 64 + o] = val;
                    } else {
                        int d = o - 64;
                        int dsw = (((d >> 3) ^ (n & 7)) << 3) | (d & 7);
                        kbuf[(((size_t)b * 72 + (n >> 5)) * 32 + (n & 31)) * 64 + dsw] = val;
                    }
                }
        }
    } else {
#pragma unroll
        for (int rt = 0; rt < 8; ++rt)
#pragma unroll
            for (int r = 0; r < 4; ++r) {
                int c = (type - 1) * 128 + rt * 16 + quad * 4 + r;
                float bias = bv[c];
#pragma unroll
                for (int ct = 0; ct < 2; ++ct) {
                    int m = r0 + wave * 32 + ct * 16 + l16;
                    vbuf2[(((size_t)b * 72 + (m >> 5)) * 512 + c) * 40 + (m & 31)] = (__bf16)(acc[rt][ct][r] + bias);
                }
            }
    }
}

// ---------------------------------------------------------------------------
// K3: flash attention, n128 x c128 tile, Tm=32, software-pipelined (R3), now
// 2 WAVES x 64 n-rows each (was 4 x 32). Rationale: kernel is LDS-BW-bound;
// every wave ingests the full V tile (8KB) + K tile (4KB) per iter regardless
// of its row count, so fewer/fatter waves halve the shared-operand re-reads:
// block-iter LDS drops 78KB -> 54KB while MFMA per wave-iter doubles (48).
// Pipeline unchanged: body(i) = PV(i) interleaved with QK^T(i+1)+exp+P.
// K(i+2)->K(i)'s slot, V(i+1)->V(i-1)'s slot, one barrier per body.
// LDS 39.4KB -> 4 blocks/CU; VGPR ~2x (acc 4x8 f32x4, mostly AGPR) -> 2 waves/SIMD.
__global__ __launch_bounds__(128, 2) void attn_kernel(const __bf16* __restrict__ qbuf,
                                                      const __bf16* __restrict__ kbuf,
                                                      const __bf16* __restrict__ vbuf2,
                                                      const float* __restrict__ x,
                                                      const float* __restrict__ gamma,
                                                      float* __restrict__ out) {
    __shared__ __align__(16) __bf16 K_lds[2][32 * 64];    //  8.0 KB
    __shared__ __align__(16) __bf16 V_lds[2][128 * 40];   // 20.0 KB
    __shared__ __align__(16) __bf16 P_lds[128 * 40];      // 10.0 KB (64 rows/wave, private)
    __shared__ float rs_lds[128];                         //  0.5 KB

    int n0 = blockIdx.x * 128, c0 = blockIdx.y * 128, b = blockIdx.z;
    int t = threadIdx.x, wave = t >> 6, lane = t & 63, quad = lane >> 4, l16 = lane & 15;
    const __bf16* q_b    = qbuf + (size_t)b * kHW * 64;
    const __bf16* k_base = kbuf + (size_t)b * 72 * 32 * 64;

    // Q fragments (held all kernel): wave owns S rows 64*wave .. +63 (B-operand of swapped QK^T)
    bf16x8 aq[4][2];
#pragma unroll
    for (int rt = 0; rt < 4; ++rt)
#pragma unroll
        for (int dk = 0; dk < 2; ++dk)
            aq[rt][dk] = *(const bf16x8*)(q_b + (size_t)(n0 + wave * 64 + rt * 16 + l16) * 64 + dk * 32 + quad * 8);

    // acc[rt][ct]: n = n0 + 64*wave + rt*16 + quad*4 + r,  c = c0 + ct*16 + l16
    f32x4 acc[4][8];
#pragma unroll
    for (int i = 0; i < 4; ++i)
#pragma unroll
        for (int j = 0; j < 8; ++j) acc[i][j] = (f32x4){0.f, 0.f, 0.f, 0.f};
    float rsum[4] = {0.f, 0.f, 0.f, 0.f};
    bf16x8 pf[4];   // P(i) fragments, materialized one body ahead

    auto issue_K = [&](int i, int buf) {
        const __bf16* ks = k_base + (size_t)i * 32 * 64;                      // 4 KB tile
        for (int ch = wave; ch < 4; ch += 2)
            dma16(ks + ch * 512 + lane * 8, &K_lds[buf][ch * 512]);
    };
    auto issue_V = [&](int i, int buf) {
        const __bf16* vs = vbuf2 + (((size_t)b * 72 + i) * 512 + c0) * 40;    // 10 KB tile
        for (int ch = wave; ch < 10; ch += 2)
            dma16(vs + ch * 512 + lane * 8, &V_lds[buf][ch * 512]);
    };
    // QK^T(j) from K_lds[j&1] -> exp2 -> P_lds (wave-private 64 rows) -> pf regs
    auto qk_phase = [&](int j) {
        int kb_ = j & 1;
        __bf16* prow = &P_lds[(wave * 64 + l16) * 40 + quad * 4];
#pragma unroll
        for (int mt = 0; mt < 2; ++mt) {
            int row = mt * 16 + l16;
            int sw = (row & 7) << 3;
            bf16x8 kf0 = *(const bf16x8*)(&K_lds[kb_][row * 64 + ((quad * 8) ^ sw)]);
            bf16x8 kf1 = *(const bf16x8*)(&K_lds[kb_][row * 64 + ((32 + quad * 8) ^ sw)]);
#pragma unroll
            for (int rt = 0; rt < 4; ++rt) {
                f32x4 s = (f32x4){0.f, 0.f, 0.f, 0.f};
                s = __builtin_amdgcn_mfma_f32_16x16x32_bf16(kf0, aq[rt][0], s, 0, 0, 0);
                s = __builtin_amdgcn_mfma_f32_16x16x32_bf16(kf1, aq[rt][1], s, 0, 0, 0);
                bf16x4 pv;
                float part = 0.f;
#pragma unroll
                for (int r = 0; r < 4; ++r) {
                    float e = EXP2(s[r]);         // Q pre-scaled by log2(e)
                    pv[r] = (__bf16)e;
                    part += e;                    // f32 sum: no bf16->f32 reconvert
                }
                rsum[rt] += part;
                *(bf16x4*)(prow + rt * 16 * 40 + mt * 16) = pv;   // ds_write_b64
            }
        }
#pragma unroll
        for (int rt = 0; rt < 4; ++rt)
            pf[rt] = *(const bf16x8*)(&P_lds[(wave * 64 + rt * 16 + l16) * 40 + quad * 8]);
    };

    // prologue: stage K(0),V(0),K(1); materialize P(0)
    issue_K(0, 0);
    issue_V(0, 0);
    issue_K(1, 1);
    __syncthreads();            // drain prologue DMAs
    qk_phase(0);

    for (int i = 0; i < 72; ++i) {
        __syncthreads();        // drains DMAs issued last body; guards buffer reuse
        if (i + 2 < 72) issue_K(i + 2, i & 1);          // K(i)'s old slot
        if (i + 1 < 72) issue_V(i + 1, (i + 1) & 1);    // V(i-1)'s old slot

        // PV(i): 32 independent MFMAs on pf (regs) x V(i) -- overlaps the
        // QK(i+1)+exp chain below (compiler-scheduled, separate pipes).
        __builtin_amdgcn_s_setprio(1);
#pragma unroll
        for (int ct = 0; ct < 8; ++ct) {
            bf16x8 vf = *(const bf16x8*)(&V_lds[i & 1][(ct * 16 + l16) * 40 + quad * 8]);
            acc[0][ct] = __builtin_amdgcn_mfma_f32_16x16x32_bf16(pf[0], vf, acc[0][ct], 0, 0, 0);
            acc[1][ct] = __builtin_amdgcn_mfma_f32_16x16x32_bf16(pf[1], vf, acc[1][ct], 0, 0, 0);
            acc[2][ct] = __builtin_amdgcn_mfma_f32_16x16x32_bf16(pf[2], vf, acc[2][ct], 0, 0, 0);
            acc[3][ct] = __builtin_amdgcn_mfma_f32_16x16x32_bf16(pf[3], vf, acc[3][ct], 0, 0, 0);
        }
        __builtin_amdgcn_s_setprio(0);

        // QK^T(i+1) -> exp -> P -> pf (next body's A-operand)
        if (i + 1 < 72) qk_phase(i + 1);
    }

    // rowsum: per-lane partial covers quad m-slices; reduce across quads.
#pragma unroll
    for (int rt = 0; rt < 4; ++rt) {
        float v = rsum[rt];
        v += __shfl_xor(v, 16);
        v += __shfl_xor(v, 32);
        if (quad == 0) rs_lds[wave * 64 + rt * 16 + l16] = v;
    }
    __syncthreads();

    float g = gamma[0];
    const float* x_b = x + (size_t)b * kC * kHW;
    float* out_b = out + (size_t)b * kC * kHW;
#pragma unroll
    for (int rt = 0; rt < 4; ++rt) {
        float inv[4];
#pragma unroll
        for (int r = 0; r < 4; ++r) inv[r] = 1.f / rs_lds[wave * 64 + rt * 16 + quad * 4 + r];
#pragma unroll
        for (int ct = 0; ct < 8; ++ct) {
            int c = c0 + ct * 16 + l16;
            size_t base = (size_t)c * kHW + n0 + wave * 64 + rt * 16 + quad * 4;
            f32x4 xin = *(const f32x4*)(x_b + base);
            f32x4 y;
#pragma unroll
            for (int r = 0; r < 4; ++r) y[r] = g * acc[rt][ct][r] * inv[r] + xin[r];
            *(f32x4*)(out_b + base) = y;
        }
    }
}

// ---------------------------------------------------------------------------
extern "C" void kernel_launch(void* const* d_in, const int* in_sizes, int n_in,
                              void* d_out, int out_size, void* d_ws, size_t ws_size,
                              hipStream_t stream) {
    const float* x     = (const float*)d_in[0];
    const float* Wq    = (const float*)d_in[1];
    const float* bq    = (const float*)d_in[2];
    const float* Wk    = (const float*)d_in[3];
    const float* bk    = (const float*)d_in[4];
    const float* Wv    = (const float*)d_in[5];
    const float* bv    = (const float*)d_in[6];
    const float* gamma = (const float*)d_in[7];
    float* out = (float*)d_out;

    char* ws = (char*)d_ws;
    __bf16* XT2   = (__bf16*)(ws);                 // 16*8*2304*72*2   = 42,467,328
    __bf16* Wqk2  = (__bf16*)(ws + 42467328);      // 8*128*72*2      =    147,456
    __bf16* Wvb2  = (__bf16*)(ws + 42614784);      // 8*512*72*2      =    589,824
    __bf16* qbuf  = (__bf16*)(ws + 43204608);      // 16*2304*64*2    =  4,718,592
    __bf16* kbuf  = (__bf16*)(ws + 47923200);      // 16*72*32*64*2   =  4,718,592
    __bf16* vbuf2 = (__bf16*)(ws + 52641792);      // 16*72*512*40*2  = 47,185,920
    // total = 99,827,712 bytes

    hipLaunchKernelGGL(pack_weights, dim3(1024), dim3(256), 0, stream, Wq, Wk, Wv, Wqk2, Wvb2);
    hipLaunchKernelGGL(pack_x, dim3(36, 8, 16), dim3(256), 0, stream, x, XT2);
    hipLaunchKernelGGL(qkv_gemm, dim3(18, 5, 16), dim3(256), 0, stream,
                       XT2, Wqk2, Wvb2, bq, bk, bv, qbuf, kbuf, vbuf2);
    hipLaunchKernelGGL(attn_kernel, dim3(18, 4, 16), dim3(128), 0, stream,
                       qbuf, kbuf, vbuf2, x, gamma, out);
}

// Round 5
// 374.491 us; speedup vs baseline: 1.1176x; 1.1176x over previous
//
#include <hip/hip_runtime.h>

typedef __bf16 bf16x8 __attribute__((ext_vector_type(8)));
typedef __bf16 bf16x4 __attribute__((ext_vector_type(4)));
typedef float  f32x4  __attribute__((ext_vector_type(4)));

constexpr int kHW = 2304;   // 48*48
constexpr int kC  = 512;

#if __has_builtin(__builtin_amdgcn_exp2f)
#define EXP2(x) __builtin_amdgcn_exp2f(x)
#else
#define EXP2(x) exp2f(x)
#endif

// async global->LDS, 16B per lane. gptr per-lane (base + lane*16B), lptr wave-uniform chunk base.
__device__ __forceinline__ void dma16(const __bf16* g, __bf16* l) {
    __builtin_amdgcn_global_load_lds(
        (const volatile __attribute__((address_space(1))) void*)g,
        (volatile __attribute__((address_space(3))) void*)l, 16, 0, 0);
}

// ---------------------------------------------------------------------------
// K0: weights -> bf16, padded tile-major layouts.
// Wqk2 [kblk=8][128 o][72], Wvb2 [kblk=8][512 c][72]  (cols 64..71 = unused pad)
__global__ void pack_weights(const float* __restrict__ Wq, const float* __restrict__ Wk,
                             const float* __restrict__ Wv, __bf16* __restrict__ Wqk2,
                             __bf16* __restrict__ Wvb2) {
    int idx = blockIdx.x * 256 + threadIdx.x;    // grid 1024 -> 262144
    int o = idx >> 9, k = idx & 511, kb = k >> 6, kr = k & 63;
    if (idx < 64 * 512) {
        Wqk2[((size_t)kb * 128 + o) * 72 + kr]      = (__bf16)Wq[idx];
        Wqk2[((size_t)kb * 128 + 64 + o) * 72 + kr] = (__bf16)Wk[idx];
    }
    if (idx < 512 * 512)
        Wvb2[((size_t)kb * 512 + o) * 72 + kr] = (__bf16)Wv[idx];
}

// ---------------------------------------------------------------------------
// K1: x [B][C][HW] fp32 -> XT2 [b][kblk=8][2304 n][72] bf16 (c-inner, padded rows)
__global__ void pack_x(const float* __restrict__ x, __bf16* __restrict__ XT2) {
    __shared__ __bf16 tile[64][65];              // [c][n]
    int n0 = blockIdx.x * 64, kblk = blockIdx.y, b = blockIdx.z;
    int c0 = kblk * 64;
    int t = threadIdx.x;
    const float* xb = x + (size_t)b * kC * kHW;
#pragma unroll
    for (int rep = 0; rep < 16; ++rep) {
        int c_loc = rep * 4 + (t >> 6);
        int n_loc = t & 63;
        tile[c_loc][n_loc] = (__bf16)xb[(size_t)(c0 + c_loc) * kHW + n0 + n_loc];
    }
    __syncthreads();
    __bf16* dst = XT2 + ((size_t)b * 8 + kblk) * kHW * 72;
#pragma unroll
    for (int rep = 0; rep < 2; ++rep) {
        int item = rep * 256 + t;                // 512 items = 64 n x 8 chunks
        int n_loc = item >> 3, chunk = item & 7;
        bf16x8 v;
#pragma unroll
        for (int j = 0; j < 8; ++j) v[j] = tile[chunk * 8 + j][n_loc];
        *(bf16x8*)(dst + (size_t)(n0 + n_loc) * 72 + chunk * 8) = v;
    }
}

// ---------------------------------------------------------------------------
// K2: QKV projections, m97-style: DMA-staged LDS tiles, BK=64, 2 barriers/iter.
//  type 0:  rows n (A=XT2), cols o (B=Wqk2) -> qbuf [b][n][64] / kbuf (32-row tiles, XOR-swz)
//  type>=1: rows c (A=Wvb2), cols m (B=XT2) -> vbuf2 [b][mblk=72][512 c][40]
// NOTE: Q outputs are pre-scaled by log2(e) so attn can use raw exp2.
// kbuf tile layout: [b][mblk=72][32 m][64 d] with d-slot XOR: elem (m,d) at
//   m*64 + ((d>>3 ^ (m&7))<<3) + (d&7)   -- inverse-swizzled source so the
//   linear global_load_lds DMA lands a bank-conflict-free pattern in LDS.
// GRID: 1D 1440 with XCD-aware swizzle. work = (bid&7)*180 + (bid>>3);
//   type = work%5 (fastest: 5 blocks sharing the same XT2 rows are adjacent),
//   r0 = (work/5)%18, b = work/90. Each XCD owns 2 whole batches -> XT2 slice
//   (2.65 MB/batch) is fetched once per XCD instead of 8x.
__global__ __launch_bounds__(256) void qkv_gemm(const __bf16* __restrict__ XT2,
                                                const __bf16* __restrict__ Wqk2,
                                                const __bf16* __restrict__ Wvb2,
                                                const float* __restrict__ bq,
                                                const float* __restrict__ bk,
                                                const float* __restrict__ bv,
                                                __bf16* __restrict__ qbuf,
                                                __bf16* __restrict__ kbuf,
                                                __bf16* __restrict__ vbuf2) {
    __shared__ __align__(16) __bf16 A_lds[128 * 72];
    __shared__ __align__(16) __bf16 B_lds[128 * 72];
    int bid = blockIdx.x;                         // 1440 = 8 XCD * 180
    int work = (bid & 7) * 180 + (bid >> 3);
    int type = work % 5;
    int g = work / 5;                             // 0..287
    int r0 = (g % 18) * 128;
    int b = g / 18;
    int t = threadIdx.x, wave = t >> 6, lane = t & 63, quad = lane >> 4, l16 = lane & 15;

    f32x4 acc[8][2];
#pragma unroll
    for (int i = 0; i < 8; ++i)
#pragma unroll
        for (int j = 0; j < 2; ++j) acc[i][j] = (f32x4){0.f, 0.f, 0.f, 0.f};

    for (int kb = 0; kb < 8; ++kb) {
        const __bf16* Asrc;
        const __bf16* Bsrc;
        if (type == 0) {
            Asrc = XT2 + (((size_t)b * 8 + kb) * kHW + r0) * 72;
            Bsrc = Wqk2 + (size_t)kb * 128 * 72;
        } else {
            Asrc = Wvb2 + ((size_t)kb * 512 + (type - 1) * 128) * 72;
            Bsrc = XT2 + (((size_t)b * 8 + kb) * kHW + r0) * 72;
        }
        __syncthreads();                          // previous iter's LDS reads done
        for (int ch = wave; ch < 18; ch += 4) {   // 18 KB per matrix, 1KB/call
            dma16(Asrc + ch * 512 + lane * 8, &A_lds[ch * 512]);
            dma16(Bsrc + ch * 512 + lane * 8, &B_lds[ch * 512]);
        }
        __syncthreads();                          // DMA complete
#pragma unroll
        for (int dk = 0; dk < 2; ++dk) {
            bf16x8 bfr[2];
#pragma unroll
            for (int ct = 0; ct < 2; ++ct)
                bfr[ct] = *(const bf16x8*)(&B_lds[(wave * 32 + ct * 16 + l16) * 72 + dk * 32 + quad * 8]);
#pragma unroll
            for (int rt = 0; rt < 8; ++rt) {
                bf16x8 a = *(const bf16x8*)(&A_lds[(rt * 16 + l16) * 72 + dk * 32 + quad * 8]);
#pragma unroll
                for (int ct = 0; ct < 2; ++ct)
                    acc[rt][ct] = __builtin_amdgcn_mfma_f32_16x16x32_bf16(a, bfr[ct], acc[rt][ct], 0, 0, 0);
            }
        }
    }

    if (type == 0) {
        constexpr float kLog2e = 1.4426950408889634f;
#pragma unroll
        for (int ct = 0; ct < 2; ++ct) {
            int o = wave * 32 + ct * 16 + l16;
            float bias = (o < 64) ? bq[o] : bk[o - 64];
            float scale = (o < 64) ? kLog2e : 1.0f;   // fold ln2 into Q
#pragma unroll
            for (int rt = 0; rt < 8; ++rt)
#pragma unroll
                for (int r = 0; r < 4; ++r) {
                    int n = r0 + rt * 16 + quad * 4 + r;
                    __bf16 val = (__bf16)((acc[rt][ct][r] + bias) * scale);
                    if (o < 64) {
                        qbuf[((size_t)b * kHW + n) * 64 + o] = val;
                    } else {
                        int d = o - 64;
                        int dsw = (((d >> 3) ^ (n & 7)) << 3) | (d & 7);
                        kbuf[(((size_t)b * 72 + (n >> 5)) * 32 + (n & 31)) * 64 + dsw] = val;
                    }
                }
        }
    } else {
#pragma unroll
        for (int rt = 0; rt < 8; ++rt)
#pragma unroll
            for (int r = 0; r < 4; ++r) {
                int c = (type - 1) * 128 + rt * 16 + quad * 4 + r;
                float bias = bv[c];
#pragma unroll
                for (int ct = 0; ct < 2; ++ct) {
                    int m = r0 + wave * 32 + ct * 16 + l16;
                    vbuf2[(((size_t)b * 72 + (m >> 5)) * 512 + c) * 40 + (m & 31)] = (__bf16)(acc[rt][ct][r] + bias);
                }
            }
    }
}

// ---------------------------------------------------------------------------
// K3: flash attention, n128 x c128 tile, Tm=32, 4 waves x 32 rows (R3 best),
// software-pipelined one tile deep: body(i) = PV(i) interleaved with
// QK^T(i+1)+exp+P. K(i+2)->K(i)'s slot, V(i+1)->V(i-1)'s slot, one barrier
// per body. 4 blocks/CU (LDS 39,424 B).
// GRID: 1D 1152 with XCD-aware swizzle. work = (bid&7)*144 + (bid>>3);
//   n0 = work%18 (fastest: the 18 blocks sharing one (c0,b) V panel are
//   co-resident on ONE XCD's L2), pair = work/18, c0 = pair&3, b = pair>>2
//   (all 4 c0 of a batch on the same XCD -> K/q panels fetched once per XCD).
__global__ __launch_bounds__(256, 4) void attn_kernel(const __bf16* __restrict__ qbuf,
                                                      const __bf16* __restrict__ kbuf,
                                                      const __bf16* __restrict__ vbuf2,
                                                      const float* __restrict__ x,
                                                      const float* __restrict__ gamma,
                                                      float* __restrict__ out) {
    __shared__ __align__(16) __bf16 K_lds[2][32 * 64];    //  8.0 KB
    __shared__ __align__(16) __bf16 V_lds[2][128 * 40];   // 20.0 KB
    __shared__ __align__(16) __bf16 P_lds[128 * 40];      // 10.0 KB (32 rows/wave, private)
    __shared__ float rs_lds[128];                         //  0.5 KB

    int bid = blockIdx.x;                         // 1152 = 8 XCD * 144
    int work = (bid & 7) * 144 + (bid >> 3);
    int n0 = (work % 18) * 128;
    int pair = work / 18;                         // 0..63
    int c0 = (pair & 3) * 128;
    int b = pair >> 2;
    int t = threadIdx.x, wave = t >> 6, lane = t & 63, quad = lane >> 4, l16 = lane & 15;
    const __bf16* q_b    = qbuf + (size_t)b * kHW * 64;
    const __bf16* k_base = kbuf + (size_t)b * 72 * 32 * 64;

    // Q fragments (held all kernel): wave owns S rows 32*wave .. +31 (B-operand of swapped QK^T)
    bf16x8 aq[2][2];
#pragma unroll
    for (int rt2 = 0; rt2 < 2; ++rt2)
#pragma unroll
        for (int dk = 0; dk < 2; ++dk)
            aq[rt2][dk] = *(const bf16x8*)(q_b + (size_t)(n0 + wave * 32 + rt2 * 16 + l16) * 64 + dk * 32 + quad * 8);

    // acc[rt2][ct]: n = n0 + 32*wave + rt2*16 + quad*4 + r,  c = c0 + ct*16 + l16
    f32x4 acc[2][8];
#pragma unroll
    for (int i = 0; i < 2; ++i)
#pragma unroll
        for (int j = 0; j < 8; ++j) acc[i][j] = (f32x4){0.f, 0.f, 0.f, 0.f};
    float rsum[2] = {0.f, 0.f};
    bf16x8 pf[2];   // P(i) fragments, materialized one body ahead

    auto issue_K = [&](int i, int buf) {
        const __bf16* ks = k_base + (size_t)i * 32 * 64;                      // 4 KB tile
        dma16(ks + wave * 512 + lane * 8, &K_lds[buf][wave * 512]);
    };
    auto issue_V = [&](int i, int buf) {
        const __bf16* vs = vbuf2 + (((size_t)b * 72 + i) * 512 + c0) * 40;    // 10 KB tile
        for (int ch = wave; ch < 10; ch += 4)
            dma16(vs + ch * 512 + lane * 8, &V_lds[buf][ch * 512]);
    };
    // QK^T(j) from K_lds[j&1] -> exp2 -> P_lds (wave-private) -> pf regs
    auto qk_phase = [&](int j) {
        int kb_ = j & 1;
        __bf16* prow = &P_lds[(wave * 32 + l16) * 40 + quad * 4];
#pragma unroll
        for (int mt = 0; mt < 2; ++mt) {
            int row = mt * 16 + l16;
            int sw = (row & 7) << 3;
            bf16x8 kf0 = *(const bf16x8*)(&K_lds[kb_][row * 64 + ((quad * 8) ^ sw)]);
            bf16x8 kf1 = *(const bf16x8*)(&K_lds[kb_][row * 64 + ((32 + quad * 8) ^ sw)]);
#pragma unroll
            for (int rt2 = 0; rt2 < 2; ++rt2) {
                f32x4 s = (f32x4){0.f, 0.f, 0.f, 0.f};
                s = __builtin_amdgcn_mfma_f32_16x16x32_bf16(kf0, aq[rt2][0], s, 0, 0, 0);
                s = __builtin_amdgcn_mfma_f32_16x16x32_bf16(kf1, aq[rt2][1], s, 0, 0, 0);
                bf16x4 pv;
                float part = 0.f;
#pragma unroll
                for (int r = 0; r < 4; ++r) {
                    float e = EXP2(s[r]);         // Q pre-scaled by log2(e)
                    pv[r] = (__bf16)e;
                    part += e;                    // f32 sum: no bf16->f32 reconvert
                }
                rsum[rt2] += part;
                *(bf16x4*)(prow + rt2 * 16 * 40 + mt * 16) = pv;   // ds_write_b64
            }
        }
        pf[0] = *(const bf16x8*)(&P_lds[(wave * 32 + l16) * 40 + quad * 8]);
        pf[1] = *(const bf16x8*)(&P_lds[(wave * 32 + 16 + l16) * 40 + quad * 8]);
    };

    // prologue: stage K(0),V(0),K(1); materialize P(0)
    issue_K(0, 0);
    issue_V(0, 0);
    issue_K(1, 1);
    __syncthreads();            // drain prologue DMAs
    qk_phase(0);

    for (int i = 0; i < 72; ++i) {
        __syncthreads();        // drains DMAs issued last body; guards buffer reuse
        if (i + 2 < 72) issue_K(i + 2, i & 1);          // K(i)'s old slot
        if (i + 1 < 72) issue_V(i + 1, (i + 1) & 1);    // V(i-1)'s old slot

        // PV(i): 16 independent MFMAs on pf (regs) x V(i) -- overlaps the
        // QK(i+1)+exp chain below (compiler-scheduled, separate pipes).
        __builtin_amdgcn_s_setprio(1);
#pragma unroll
        for (int ct = 0; ct < 8; ++ct) {
            bf16x8 vf = *(const bf16x8*)(&V_lds[i & 1][(ct * 16 + l16) * 40 + quad * 8]);
            acc[0][ct] = __builtin_amdgcn_mfma_f32_16x16x32_bf16(pf[0], vf, acc[0][ct], 0, 0, 0);
            acc[1][ct] = __builtin_amdgcn_mfma_f32_16x16x32_bf16(pf[1], vf, acc[1][ct], 0, 0, 0);
        }
        __builtin_amdgcn_s_setprio(0);

        // QK^T(i+1) -> exp -> P -> pf (next body's A-operand)
        if (i + 1 < 72) qk_phase(i + 1);
    }

    // rowsum: per-lane partial covers quad m-slices; reduce across quads.
#pragma unroll
    for (int rt2 = 0; rt2 < 2; ++rt2) {
        float v = rsum[rt2];
        v += __shfl_xor(v, 16);
        v += __shfl_xor(v, 32);
        if (quad == 0) rs_lds[wave * 32 + rt2 * 16 + l16] = v;
    }
    __syncthreads();

    float g = gamma[0];
    const float* x_b = x + (size_t)b * kC * kHW;
    float* out_b = out + (size_t)b * kC * kHW;
#pragma unroll
    for (int rt2 = 0; rt2 < 2; ++rt2) {
        float inv[4];
#pragma unroll
        for (int r = 0; r < 4; ++r) inv[r] = 1.f / rs_lds[wave * 32 + rt2 * 16 + quad * 4 + r];
#pragma unroll
        for (int ct = 0; ct < 8; ++ct) {
            int c = c0 + ct * 16 + l16;
            size_t base = (size_t)c * kHW + n0 + wave * 32 + rt2 * 16 + quad * 4;
            f32x4 xin = *(const f32x4*)(x_b + base);
            f32x4 y;
#pragma unroll
            for (int r = 0; r < 4; ++r) y[r] = g * acc[rt2][ct][r] * inv[r] + xin[r];
            *(f32x4*)(out_b + base) = y;
        }
    }
}

// ---------------------------------------------------------------------------
extern "C" void kernel_launch(void* const* d_in, const int* in_sizes, int n_in,
                              void* d_out, int out_size, void* d_ws, size_t ws_size,
                              hipStream_t stream) {
    const float* x     = (const float*)d_in[0];
    const float* Wq    = (const float*)d_in[1];
    const float* bq    = (const float*)d_in[2];
    const float* Wk    = (const float*)d_in[3];
    const float* bk    = (const float*)d_in[4];
    const float* Wv    = (const float*)d_in[5];
    const float* bv    = (const float*)d_in[6];
    const float* gamma = (const float*)d_in[7];
    float* out = (float*)d_out;

    char* ws = (char*)d_ws;
    __bf16* XT2   = (__bf16*)(ws);                 // 16*8*2304*72*2   = 42,467,328
    __bf16* Wqk2  = (__bf16*)(ws + 42467328);      // 8*128*72*2      =    147,456
    __bf16* Wvb2  = (__bf16*)(ws + 42614784);      // 8*512*72*2      =    589,824
    __bf16* qbuf  = (__bf16*)(ws + 43204608);      // 16*2304*64*2    =  4,718,592
    __bf16* kbuf  = (__bf16*)(ws + 47923200);      // 16*72*32*64*2   =  4,718,592
    __bf16* vbuf2 = (__bf16*)(ws + 52641792);      // 16*72*512*40*2  = 47,185,920
    // total = 99,827,712 bytes

    hipLaunchKernelGGL(pack_weights, dim3(1024), dim3(256), 0, stream, Wq, Wk, Wv, Wqk2, Wvb2);
    hipLaunchKernelGGL(pack_x, dim3(36, 8, 16), dim3(256), 0, stream, x, XT2);
    hipLaunchKernelGGL(qkv_gemm, dim3(1440), dim3(256), 0, stream,
                       XT2, Wqk2, Wvb2, bq, bk, bv, qbuf, kbuf, vbuf2);
    hipLaunchKernelGGL(attn_kernel, dim3(1152), dim3(256), 0, stream,
                       qbuf, kbuf, vbuf2, x, gamma, out);
}